// Round 8
// baseline (45.990 us; speedup 1.0000x reference)
//
#include <hip/hip_runtime.h>
#include <cstdint>
#include <cstddef>

#define ROW_L   512
#define ROW_L4  128
#define K1_TPB  512
#define K1_WAVES (K1_TPB/64)
#define NB      256

__device__ __forceinline__ unsigned int f32_sortable(float f) {
    unsigned int u = __float_as_uint(f);
    return (u & 0x80000000u) ? ~u : (u | 0x80000000u);
}
__device__ __forceinline__ unsigned long long pack_ki(float key, int idx) {
    return (((unsigned long long)f32_sortable(key)) << 32)
         | (unsigned long long)(0xFFFFFFFFu - (unsigned int)idx);
}

// Main pass (round-5 core, 2-row unroll per half-wave for 2x memory-level
// parallelism): half-wave (32 lanes) processes rows r and r+1 per iteration.
//   d0,d1 = x.linear cols -> ins_probs; g0,g1 = x.fbank cols -> pred -> e=exp(s-C).
// Per-block: fpart = sum e*x, spart = sum e, argmax key, ylpart = fpart_b @ linear.
__global__ __launch_bounds__(K1_TPB) void k1_main(
    const float* __restrict__ x, const float* __restrict__ y,
    const float* __restrict__ linear, const float* __restrict__ fbank,
    const float* __restrict__ w_ps, const float* __restrict__ b_ps,
    float* __restrict__ out,
    float* __restrict__ fpart, float* __restrict__ spart,
    float* __restrict__ akey, int* __restrict__ aidx,
    float2* __restrict__ ylpart,
    int N)
{
    const int tid  = threadIdx.x;
    const int wid  = tid >> 6;
    const int lane = tid & 63;
    const int h    = lane >> 5;   // which half-wave
    const int hl   = lane & 31;   // lane within half

    const float4* __restrict__ x4 = (const float4*)x;
    const float4* __restrict__ l4 = (const float4*)linear;
    const float4* __restrict__ f4 = (const float4*)fbank;

    // Register-cached weights: lane hl covers float4-groups p = hl + 32k (k=0..3).
    // (512,2) row-major: float4 idx 2p,2p+1 hold cols interleaved {c0,c1,c0,c1}.
    float4 lw[4][2], fw[4][2];
#pragma unroll
    for (int k = 0; k < 4; ++k) {
        const int p = hl + 32*k;
        lw[k][0] = l4[2*p]; lw[k][1] = l4[2*p+1];
        fw[k][0] = f4[2*p]; fw[k][1] = f4[2*p+1];
    }
    const float w0 = w_ps[0], w1 = w_ps[1], bb = b_ps[0];
    const float C  = bb + fmaxf(w0, w1);          // e = exp(s-C) in (0,1]
    const int yidx = (y[1] > y[0]) ? 1 : 0;

    float4 facc[4];
#pragma unroll
    for (int k=0;k<4;++k) facc[k] = make_float4(0.f,0.f,0.f,0.f);
    float sum_e   = 0.f;
    float bestKey = -INFINITY;
    int   bestIdx = 0x7FFFFFFF;

    const int gw = blockIdx.x * K1_WAVES + wid;
    const int NW = NB * K1_WAVES;
    float* __restrict__ out_alpha = out + 3;
    float* __restrict__ out_ins   = out + 3 + (size_t)N;

    // each half-wave handles rows {r0, r0+1}; wave covers 4 rows/iter
    for (int r0 = gw*4 + 2*h; r0 < N; r0 += NW*4) {
        const int r1 = r0 + 1;
        const bool has1 = (r1 < N);
        const float4* __restrict__ xr0 = x4 + (size_t)r0 * ROW_L4;
        const float4* __restrict__ xr1 = x4 + (size_t)(has1 ? r1 : r0) * ROW_L4;
        float4 xa[4], xc[4];
#pragma unroll
        for (int k=0;k<4;++k) xa[k] = xr0[hl + 32*k];
#pragma unroll
        for (int k=0;k<4;++k) xc[k] = xr1[hl + 32*k];

        float d0a=0.f,d1a=0.f,g0a=0.f,g1a=0.f;
        float d0b=0.f,d1b=0.f,g0b=0.f,g1b=0.f;
#pragma unroll
        for (int k=0;k<4;++k) {
            d0a = fmaf(xa[k].x, lw[k][0].x, d0a);
            d0a = fmaf(xa[k].y, lw[k][0].z, d0a);
            d0a = fmaf(xa[k].z, lw[k][1].x, d0a);
            d0a = fmaf(xa[k].w, lw[k][1].z, d0a);
            d1a = fmaf(xa[k].x, lw[k][0].y, d1a);
            d1a = fmaf(xa[k].y, lw[k][0].w, d1a);
            d1a = fmaf(xa[k].z, lw[k][1].y, d1a);
            d1a = fmaf(xa[k].w, lw[k][1].w, d1a);
            g0a = fmaf(xa[k].x, fw[k][0].x, g0a);
            g0a = fmaf(xa[k].y, fw[k][0].z, g0a);
            g0a = fmaf(xa[k].z, fw[k][1].x, g0a);
            g0a = fmaf(xa[k].w, fw[k][1].z, g0a);
            g1a = fmaf(xa[k].x, fw[k][0].y, g1a);
            g1a = fmaf(xa[k].y, fw[k][0].w, g1a);
            g1a = fmaf(xa[k].z, fw[k][1].y, g1a);
            g1a = fmaf(xa[k].w, fw[k][1].w, g1a);
            d0b = fmaf(xc[k].x, lw[k][0].x, d0b);
            d0b = fmaf(xc[k].y, lw[k][0].z, d0b);
            d0b = fmaf(xc[k].z, lw[k][1].x, d0b);
            d0b = fmaf(xc[k].w, lw[k][1].z, d0b);
            d1b = fmaf(xc[k].x, lw[k][0].y, d1b);
            d1b = fmaf(xc[k].y, lw[k][0].w, d1b);
            d1b = fmaf(xc[k].z, lw[k][1].y, d1b);
            d1b = fmaf(xc[k].w, lw[k][1].w, d1b);
            g0b = fmaf(xc[k].x, fw[k][0].x, g0b);
            g0b = fmaf(xc[k].y, fw[k][0].z, g0b);
            g0b = fmaf(xc[k].z, fw[k][1].x, g0b);
            g0b = fmaf(xc[k].w, fw[k][1].z, g0b);
            g1b = fmaf(xc[k].x, fw[k][0].y, g1b);
            g1b = fmaf(xc[k].y, fw[k][0].w, g1b);
            g1b = fmaf(xc[k].z, fw[k][1].y, g1b);
            g1b = fmaf(xc[k].w, fw[k][1].w, g1b);
        }
        // reduce the 8 dots within the 32-lane half (independent chains interleave)
#pragma unroll
        for (int off = 16; off >= 1; off >>= 1) {
            d0a += __shfl_xor(d0a, off, 32);
            d1a += __shfl_xor(d1a, off, 32);
            g0a += __shfl_xor(g0a, off, 32);
            g1a += __shfl_xor(g1a, off, 32);
            d0b += __shfl_xor(d0b, off, 32);
            d1b += __shfl_xor(d1b, off, 32);
            g0b += __shfl_xor(g0b, off, 32);
            g1b += __shfl_xor(g1b, off, 32);
        }
        // ---- row r0 ----
        {
            const float mi = fmaxf(d0a, d1a);
            const float e0 = __expf(d0a - mi), e1 = __expf(d1a - mi);
            const float iinv = 1.f / (e0 + e1);
            const float mp = fmaxf(g0a, g1a);
            const float q0 = __expf(g0a - mp), q1 = __expf(g1a - mp);
            const float pinv = 1.f / (q0 + q1);
            const float s = fmaf(q0*pinv, w0, fmaf(q1*pinv, w1, bb));
            const float e = __expf(s - C);
            sum_e += e;
#pragma unroll
            for (int k=0;k<4;++k) {
                facc[k].x = fmaf(e, xa[k].x, facc[k].x);
                facc[k].y = fmaf(e, xa[k].y, facc[k].y);
                facc[k].z = fmaf(e, xa[k].z, facc[k].z);
                facc[k].w = fmaf(e, xa[k].w, facc[k].w);
            }
            const float key = yidx ? (g1a - g0a) : (g0a - g1a);
            if (key > bestKey) { bestKey = key; bestIdx = r0; }
            if (hl == 0) {
                out_alpha[r0] = e;
                out_ins[2*(size_t)r0]   = e0 * iinv;
                out_ins[2*(size_t)r0+1] = e1 * iinv;
            }
        }
        // ---- row r1 ----
        if (has1) {
            const float mi = fmaxf(d0b, d1b);
            const float e0 = __expf(d0b - mi), e1 = __expf(d1b - mi);
            const float iinv = 1.f / (e0 + e1);
            const float mp = fmaxf(g0b, g1b);
            const float q0 = __expf(g0b - mp), q1 = __expf(g1b - mp);
            const float pinv = 1.f / (q0 + q1);
            const float s = fmaf(q0*pinv, w0, fmaf(q1*pinv, w1, bb));
            const float e = __expf(s - C);
            sum_e += e;
#pragma unroll
            for (int k=0;k<4;++k) {
                facc[k].x = fmaf(e, xc[k].x, facc[k].x);
                facc[k].y = fmaf(e, xc[k].y, facc[k].y);
                facc[k].z = fmaf(e, xc[k].z, facc[k].z);
                facc[k].w = fmaf(e, xc[k].w, facc[k].w);
            }
            const float key = yidx ? (g1b - g0b) : (g0b - g1b);
            if (key > bestKey) { bestKey = key; bestIdx = r1; }
            if (hl == 0) {
                out_alpha[r1] = e;
                out_ins[2*(size_t)r1]   = e0 * iinv;
                out_ins[2*(size_t)r1+1] = e1 * iinv;
            }
        }
    }
    // combine the wave's two halves
#pragma unroll
    for (int k=0;k<4;++k) {
        facc[k].x += __shfl_xor(facc[k].x, 32);
        facc[k].y += __shfl_xor(facc[k].y, 32);
        facc[k].z += __shfl_xor(facc[k].z, 32);
        facc[k].w += __shfl_xor(facc[k].w, 32);
    }
    sum_e += __shfl_xor(sum_e, 32);
    {
        const float ok = __shfl_xor(bestKey, 32);
        const int   oi = __shfl_xor(bestIdx, 32);
        if (ok > bestKey || (ok == bestKey && oi < bestIdx)) { bestKey = ok; bestIdx = oi; }
    }
    // deterministic block reduction via LDS (no atomics)
    __shared__ float4 lfa[K1_WAVES][ROW_L4];   // 16 KiB
    __shared__ float  lse[K1_WAVES];
    __shared__ float  lbk[K1_WAVES];
    __shared__ int    lbi[K1_WAVES];
    __shared__ float2 ylred[K1_TPB];           // 4 KiB
    if (h == 0) {
#pragma unroll
        for (int k=0;k<4;++k) lfa[wid][hl + 32*k] = facc[k];
        if (hl == 0) { lse[wid] = sum_e; lbk[wid] = bestKey; lbi[wid] = bestIdx; }
    }
    __syncthreads();
    float acc = 0.f;
    const float* lfaf = (const float*)lfa;
#pragma unroll
    for (int w=0; w<K1_WAVES; ++w) acc += lfaf[w*ROW_L + tid];
    fpart[(size_t)blockIdx.x * ROW_L + tid] = acc;
    // per-block Y_logit contribution: yl_b[j] = sum_t acc_t * linear[2t+j]
    ylred[tid] = make_float2(acc * linear[2*tid], acc * linear[2*tid+1]);
    __syncthreads();
    for (int s = 256; s > 0; s >>= 1) {
        if (tid < s) { ylred[tid].x += ylred[tid+s].x; ylred[tid].y += ylred[tid+s].y; }
        __syncthreads();
    }
    if (tid == 0) {
        ylpart[blockIdx.x] = ylred[0];
        float se = 0.f;
        float bk = lbk[0]; int bi = lbi[0];
#pragma unroll
        for (int w=0; w<K1_WAVES; ++w) se += lse[w];
        for (int w=1; w<K1_WAVES; ++w)
            if (lbk[w] > bk || (lbk[w] == bk && lbi[w] < bi)) { bk = lbk[w]; bi = lbi[w]; }
        spart[blockIdx.x] = se;
        akey[blockIdx.x]  = bk;
        aidx[blockIdx.x]  = bi;
    }
}

// Distributed finalize, NB+1 blocks of 512:
//   blocks 0..NB-1: S; Fagg columns {2b,2b+1}; rescale alpha slice.
//   block NB: argmax merge, Y_prob/Y_hat, fbank column update.
__global__ __launch_bounds__(512) void k2_final(
    const float* __restrict__ x, const float* __restrict__ y,
    const float* __restrict__ linear, const float* __restrict__ fbank,
    const float* __restrict__ fpart, const float* __restrict__ spart,
    const float* __restrict__ akey, const int* __restrict__ aidx,
    const float2* __restrict__ ylpart,
    float* __restrict__ out, int N)
{
    const int t = threadIdx.x, b = blockIdx.x;
    __shared__ float red[512];
    __shared__ float sS;

    // S = sum(spart) — every block computes it (1 KB, cache-resident)
    red[t] = (t < NB) ? spart[t] : 0.f;
    __syncthreads();
    for (int s = 256; s > 0; s >>= 1) { if (t < s) red[t] += red[t+s]; __syncthreads(); }
    if (t == 0) sS = red[0];
    __syncthreads();
    const float S = sS;

    float* __restrict__ out_alpha = out + 3;

    if (b < NB) {
        // Fagg columns {2b, 2b+1}: threads 0..255 -> col 2b, 256..511 -> col 2b+1
        const int half = t >> 8, tt = t & 255;
        const float v = fpart[(size_t)tt * ROW_L + 2*b + half];
        __syncthreads();
        red[t] = v;
        __syncthreads();
        for (int s = 128; s > 0; s >>= 1) {
            if ((t & 255) < s) red[t] += red[t+s];
            __syncthreads();
        }
        if ((t & 255) == 0) out[3 + 3*(size_t)N + 2*b + half] = red[t] / S;
        // rescale alpha slice
        for (int i = b*512 + t; i < N; i += NB*512) out_alpha[i] = out_alpha[i] / S;
        return;
    }

    // finals block
    __shared__ unsigned long long redu[256];
    __shared__ float sC0, sC1, sNorm;
    __shared__ int sSel;
    {
        if (t < NB) redu[t] = pack_ki(akey[t], aidx[t]);
        __syncthreads();
        for (int s = 128; s > 0; s >>= 1) {
            if (t < s) { if (redu[t+s] > redu[t]) redu[t] = redu[t+s]; }
            __syncthreads();
        }
        if (t == 0) sSel = (int)(0xFFFFFFFFu - (unsigned int)(redu[0] & 0xFFFFFFFFull));
        __syncthreads();
    }
    {
        const float2 yv = (t < NB) ? ylpart[t] : make_float2(0.f, 0.f);
        red[t] = yv.x;
        __syncthreads();
        for (int s = 256; s > 0; s >>= 1) { if (t < s) red[t] += red[t+s]; __syncthreads(); }
        if (t == 0) sC0 = red[0] / S;
        __syncthreads();
        red[t] = yv.y;
        __syncthreads();
        for (int s = 256; s > 0; s >>= 1) { if (t < s) red[t] += red[t+s]; __syncthreads(); }
        if (t == 0) sC1 = red[0] / S;
        __syncthreads();
    }
    {
        // fbank EMA update on column yidx, F.normalize(dim=0)
        const int yidx = (y[1] > y[0]) ? 1 : 0;
        const float crit = x[(size_t)sSel * ROW_L + t];
        const float fb_y = fbank[2*t + yidx];
        const float fb_o = fbank[2*t + (1-yidx)];
        const float vv = fmaf(0.99f, fb_y, 0.01f * crit);
        red[t] = vv * vv;
        __syncthreads();
        for (int s = 256; s > 0; s >>= 1) { if (t < s) red[t] += red[t+s]; __syncthreads(); }
        if (t == 0) sNorm = sqrtf(red[0]);
        __syncthreads();
        const float nf = vv / fmaxf(sNorm, 1e-12f);
        float* out_fb = out + 3 + 3*(size_t)N + ROW_L;
        out_fb[2*t + yidx]     = nf;
        out_fb[2*t + (1-yidx)] = fb_o;
    }
    if (t == 0) {
        const float c0 = sC0, c1 = sC1;
        const float m = fmaxf(c0, c1);
        const float lse2 = m + logf(expf(c0-m) + expf(c1-m));
        out[0] = c0 - lse2;
        out[1] = c1 - lse2;
        out[2] = (c1 > c0) ? 1.0f : 0.0f;   // jnp.argmax: first max -> 0 on tie
    }
}

extern "C" void kernel_launch(void* const* d_in, const int* in_sizes, int n_in,
                              void* d_out, int out_size, void* d_ws, size_t ws_size,
                              hipStream_t stream) {
    const float* x   = (const float*)d_in[0];
    const float* y   = (const float*)d_in[1];
    // d_in[2] = bag_size (unused; N derived from in_sizes)
    const float* lin = (const float*)d_in[3];
    const float* fb  = (const float*)d_in[4];
    const float* wps = (const float*)d_in[5];
    const float* bps = (const float*)d_in[6];
    float* out = (float*)d_out;
    const int N = in_sizes[0] / ROW_L;

    // ws layout: fpart[NB*512] | spart[NB] | akey[NB] | aidx[NB] | ylpart[NB] (float2)
    float*  fpart  = (float*)d_ws;
    float*  spart  = fpart + (size_t)NB * ROW_L;
    float*  akey   = spart + NB;
    int*    aidx   = (int*)(akey + NB);
    float2* ylpart = (float2*)(aidx + NB);

    k1_main<<<NB, K1_TPB, 0, stream>>>(x, y, lin, fb, wps, bps, out,
                                       fpart, spart, akey, aidx, ylpart, N);
    k2_final<<<NB + 1, 512, 0, stream>>>(x, y, lin, fb, fpart, spart, akey, aidx,
                                         ylpart, out, N);
}

// Round 9
// 43.620 us; speedup vs baseline: 1.0543x; 1.0543x over previous
//
#include <hip/hip_runtime.h>
#include <cstdint>
#include <cstddef>

#define ROW_L   512
#define ROW_L4  128
#define K1_TPB  512
#define K1_WAVES (K1_TPB/64)
#define NB      256

__device__ __forceinline__ unsigned int f32_sortable(float f) {
    unsigned int u = __float_as_uint(f);
    return (u & 0x80000000u) ? ~u : (u | 0x80000000u);
}
__device__ __forceinline__ unsigned long long pack_ki(float key, int idx) {
    return (((unsigned long long)f32_sortable(key)) << 32)
         | (unsigned long long)(0xFFFFFFFFu - (unsigned int)idx);
}

// Main pass (round-5 core, best measured): one half-wave (32 lanes) per row.
//   d0,d1 = x.linear cols -> ins_probs; g0,g1 = x.fbank cols -> pred -> e=exp(s-C).
// Per-block: fpart = sum e*x, spart = sum e, argmax key, ylpart = fpart_b @ linear.
__global__ __launch_bounds__(K1_TPB) void k1_main(
    const float* __restrict__ x, const float* __restrict__ y,
    const float* __restrict__ linear, const float* __restrict__ fbank,
    const float* __restrict__ w_ps, const float* __restrict__ b_ps,
    float* __restrict__ out,
    float* __restrict__ fpart, float* __restrict__ spart,
    float* __restrict__ akey, int* __restrict__ aidx,
    float2* __restrict__ ylpart,
    int N)
{
    const int tid  = threadIdx.x;
    const int wid  = tid >> 6;
    const int lane = tid & 63;
    const int h    = lane >> 5;   // which half-wave
    const int hl   = lane & 31;   // lane within half

    const float4* __restrict__ x4 = (const float4*)x;
    const float4* __restrict__ l4 = (const float4*)linear;
    const float4* __restrict__ f4 = (const float4*)fbank;

    // Register-cached weights: lane hl covers float4-groups p = hl + 32k (k=0..3).
    // (512,2) row-major: float4 idx 2p,2p+1 hold cols interleaved {c0,c1,c0,c1}.
    float4 lw[4][2], fw[4][2];
#pragma unroll
    for (int k = 0; k < 4; ++k) {
        const int p = hl + 32*k;
        lw[k][0] = l4[2*p]; lw[k][1] = l4[2*p+1];
        fw[k][0] = f4[2*p]; fw[k][1] = f4[2*p+1];
    }
    const float w0 = w_ps[0], w1 = w_ps[1], bb = b_ps[0];
    const float C  = bb + fmaxf(w0, w1);          // e = exp(s-C) in (0,1]
    const int yidx = (y[1] > y[0]) ? 1 : 0;

    float4 facc[4];
#pragma unroll
    for (int k=0;k<4;++k) facc[k] = make_float4(0.f,0.f,0.f,0.f);
    float sum_e   = 0.f;
    float bestKey = -INFINITY;
    int   bestIdx = 0x7FFFFFFF;

    const int gw = blockIdx.x * K1_WAVES + wid;
    const int NW = NB * K1_WAVES;
    float* __restrict__ out_alpha = out + 3;
    float* __restrict__ out_ins   = out + 3 + (size_t)N;

    for (int row = gw*2 + h; row < N; row += NW*2) {
        const float4* __restrict__ xr = x4 + (size_t)row * ROW_L4;
        float4 xa[4];
#pragma unroll
        for (int k=0;k<4;++k) xa[k] = xr[hl + 32*k];
        float d0=0.f,d1=0.f,g0=0.f,g1=0.f;
#pragma unroll
        for (int k=0;k<4;++k) {
            d0 = fmaf(xa[k].x, lw[k][0].x, d0);
            d0 = fmaf(xa[k].y, lw[k][0].z, d0);
            d0 = fmaf(xa[k].z, lw[k][1].x, d0);
            d0 = fmaf(xa[k].w, lw[k][1].z, d0);
            d1 = fmaf(xa[k].x, lw[k][0].y, d1);
            d1 = fmaf(xa[k].y, lw[k][0].w, d1);
            d1 = fmaf(xa[k].z, lw[k][1].y, d1);
            d1 = fmaf(xa[k].w, lw[k][1].w, d1);
            g0 = fmaf(xa[k].x, fw[k][0].x, g0);
            g0 = fmaf(xa[k].y, fw[k][0].z, g0);
            g0 = fmaf(xa[k].z, fw[k][1].x, g0);
            g0 = fmaf(xa[k].w, fw[k][1].z, g0);
            g1 = fmaf(xa[k].x, fw[k][0].y, g1);
            g1 = fmaf(xa[k].y, fw[k][0].w, g1);
            g1 = fmaf(xa[k].z, fw[k][1].y, g1);
            g1 = fmaf(xa[k].w, fw[k][1].w, g1);
        }
        // reduce 4 dots within the 32-lane half
#pragma unroll
        for (int off = 16; off >= 1; off >>= 1) {
            d0 += __shfl_xor(d0, off, 32);
            d1 += __shfl_xor(d1, off, 32);
            g0 += __shfl_xor(g0, off, 32);
            g1 += __shfl_xor(g1, off, 32);
        }
        // instance softmax
        const float mi = fmaxf(d0, d1);
        const float e0 = __expf(d0 - mi), e1 = __expf(d1 - mi);
        const float iinv = 1.f / (e0 + e1);
        // pred softmax -> attention scalar -> bounded-shift exp
        const float mp = fmaxf(g0, g1);
        const float q0 = __expf(g0 - mp), q1 = __expf(g1 - mp);
        const float pinv = 1.f / (q0 + q1);
        const float s = fmaf(q0*pinv, w0, fmaf(q1*pinv, w1, bb));
        const float e = __expf(s - C);
        sum_e += e;
#pragma unroll
        for (int k=0;k<4;++k) {
            facc[k].x = fmaf(e, xa[k].x, facc[k].x);
            facc[k].y = fmaf(e, xa[k].y, facc[k].y);
            facc[k].z = fmaf(e, xa[k].z, facc[k].z);
            facc[k].w = fmaf(e, xa[k].w, facc[k].w);
        }
        // argmax of pred[:,yidx] == argmax of (g_y - g_other)
        const float key = yidx ? (g1 - g0) : (g0 - g1);
        if (key > bestKey) { bestKey = key; bestIdx = row; }  // strict >: lowest row wins
        if (hl == 0) {
            out_alpha[row] = e;                 // numerator; k2 normalizes
            out_ins[2*(size_t)row]   = e0 * iinv;
            out_ins[2*(size_t)row+1] = e1 * iinv;
        }
    }
    // combine the wave's two halves
#pragma unroll
    for (int k=0;k<4;++k) {
        facc[k].x += __shfl_xor(facc[k].x, 32);
        facc[k].y += __shfl_xor(facc[k].y, 32);
        facc[k].z += __shfl_xor(facc[k].z, 32);
        facc[k].w += __shfl_xor(facc[k].w, 32);
    }
    sum_e += __shfl_xor(sum_e, 32);
    {
        const float ok = __shfl_xor(bestKey, 32);
        const int   oi = __shfl_xor(bestIdx, 32);
        if (ok > bestKey || (ok == bestKey && oi < bestIdx)) { bestKey = ok; bestIdx = oi; }
    }
    // deterministic block reduction via LDS (no atomics)
    __shared__ float4 lfa[K1_WAVES][ROW_L4];   // 16 KiB
    __shared__ float  lse[K1_WAVES];
    __shared__ float  lbk[K1_WAVES];
    __shared__ int    lbi[K1_WAVES];
    __shared__ float2 ylred[K1_TPB];           // 4 KiB
    if (h == 0) {
#pragma unroll
        for (int k=0;k<4;++k) lfa[wid][hl + 32*k] = facc[k];
        if (hl == 0) { lse[wid] = sum_e; lbk[wid] = bestKey; lbi[wid] = bestIdx; }
    }
    __syncthreads();
    float acc = 0.f;
    const float* lfaf = (const float*)lfa;
#pragma unroll
    for (int w=0; w<K1_WAVES; ++w) acc += lfaf[w*ROW_L + tid];
    fpart[(size_t)blockIdx.x * ROW_L + tid] = acc;
    // per-block Y_logit contribution: yl_b[j] = sum_t acc_t * linear[2t+j]
    ylred[tid] = make_float2(acc * linear[2*tid], acc * linear[2*tid+1]);
    __syncthreads();
    for (int s = 256; s > 0; s >>= 1) {
        if (tid < s) { ylred[tid].x += ylred[tid+s].x; ylred[tid].y += ylred[tid+s].y; }
        __syncthreads();
    }
    if (tid == 0) {
        ylpart[blockIdx.x] = ylred[0];
        float se = 0.f;
        float bk = lbk[0]; int bi = lbi[0];
#pragma unroll
        for (int w=0; w<K1_WAVES; ++w) se += lse[w];
        for (int w=1; w<K1_WAVES; ++w)
            if (lbk[w] > bk || (lbk[w] == bk && lbi[w] < bi)) { bk = lbk[w]; bi = lbi[w]; }
        spart[blockIdx.x] = se;
        akey[blockIdx.x]  = bk;
        aidx[blockIdx.x]  = bi;
    }
}

// Distributed finalize, NB+1 blocks of 512:
//   blocks 0..NB-1: S; Fagg columns {2b,2b+1}; rescale alpha slice.
//   block NB: argmax merge, Y_prob/Y_hat, fbank column update.
__global__ __launch_bounds__(512) void k2_final(
    const float* __restrict__ x, const float* __restrict__ y,
    const float* __restrict__ linear, const float* __restrict__ fbank,
    const float* __restrict__ fpart, const float* __restrict__ spart,
    const float* __restrict__ akey, const int* __restrict__ aidx,
    const float2* __restrict__ ylpart,
    float* __restrict__ out, int N)
{
    const int t = threadIdx.x, b = blockIdx.x;
    __shared__ float red[512];
    __shared__ float sS;

    // S = sum(spart) — every block computes it (1 KB, cache-resident)
    red[t] = (t < NB) ? spart[t] : 0.f;
    __syncthreads();
    for (int s = 256; s > 0; s >>= 1) { if (t < s) red[t] += red[t+s]; __syncthreads(); }
    if (t == 0) sS = red[0];
    __syncthreads();
    const float S = sS;

    float* __restrict__ out_alpha = out + 3;

    if (b < NB) {
        // Fagg columns {2b, 2b+1}: threads 0..255 -> col 2b, 256..511 -> col 2b+1
        const int half = t >> 8, tt = t & 255;
        const float v = fpart[(size_t)tt * ROW_L + 2*b + half];
        __syncthreads();
        red[t] = v;
        __syncthreads();
        for (int s = 128; s > 0; s >>= 1) {
            if ((t & 255) < s) red[t] += red[t+s];
            __syncthreads();
        }
        if ((t & 255) == 0) out[3 + 3*(size_t)N + 2*b + half] = red[t] / S;
        // rescale alpha slice
        for (int i = b*512 + t; i < N; i += NB*512) out_alpha[i] = out_alpha[i] / S;
        return;
    }

    // finals block
    __shared__ unsigned long long redu[256];
    __shared__ float sC0, sC1, sNorm;
    __shared__ int sSel;
    {
        if (t < NB) redu[t] = pack_ki(akey[t], aidx[t]);
        __syncthreads();
        for (int s = 128; s > 0; s >>= 1) {
            if (t < s) { if (redu[t+s] > redu[t]) redu[t] = redu[t+s]; }
            __syncthreads();
        }
        if (t == 0) sSel = (int)(0xFFFFFFFFu - (unsigned int)(redu[0] & 0xFFFFFFFFull));
        __syncthreads();
    }
    {
        const float2 yv = (t < NB) ? ylpart[t] : make_float2(0.f, 0.f);
        red[t] = yv.x;
        __syncthreads();
        for (int s = 256; s > 0; s >>= 1) { if (t < s) red[t] += red[t+s]; __syncthreads(); }
        if (t == 0) sC0 = red[0] / S;
        __syncthreads();
        red[t] = yv.y;
        __syncthreads();
        for (int s = 256; s > 0; s >>= 1) { if (t < s) red[t] += red[t+s]; __syncthreads(); }
        if (t == 0) sC1 = red[0] / S;
        __syncthreads();
    }
    {
        // fbank EMA update on column yidx, F.normalize(dim=0)
        const int yidx = (y[1] > y[0]) ? 1 : 0;
        const float crit = x[(size_t)sSel * ROW_L + t];
        const float fb_y = fbank[2*t + yidx];
        const float fb_o = fbank[2*t + (1-yidx)];
        const float vv = fmaf(0.99f, fb_y, 0.01f * crit);
        red[t] = vv * vv;
        __syncthreads();
        for (int s = 256; s > 0; s >>= 1) { if (t < s) red[t] += red[t+s]; __syncthreads(); }
        if (t == 0) sNorm = sqrtf(red[0]);
        __syncthreads();
        const float nf = vv / fmaxf(sNorm, 1e-12f);
        float* out_fb = out + 3 + 3*(size_t)N + ROW_L;
        out_fb[2*t + yidx]     = nf;
        out_fb[2*t + (1-yidx)] = fb_o;
    }
    if (t == 0) {
        const float c0 = sC0, c1 = sC1;
        const float m = fmaxf(c0, c1);
        const float lse2 = m + logf(expf(c0-m) + expf(c1-m));
        out[0] = c0 - lse2;
        out[1] = c1 - lse2;
        out[2] = (c1 > c0) ? 1.0f : 0.0f;   // jnp.argmax: first max -> 0 on tie
    }
}

extern "C" void kernel_launch(void* const* d_in, const int* in_sizes, int n_in,
                              void* d_out, int out_size, void* d_ws, size_t ws_size,
                              hipStream_t stream) {
    const float* x   = (const float*)d_in[0];
    const float* y   = (const float*)d_in[1];
    // d_in[2] = bag_size (unused; N derived from in_sizes)
    const float* lin = (const float*)d_in[3];
    const float* fb  = (const float*)d_in[4];
    const float* wps = (const float*)d_in[5];
    const float* bps = (const float*)d_in[6];
    float* out = (float*)d_out;
    const int N = in_sizes[0] / ROW_L;

    // ws layout: fpart[NB*512] | spart[NB] | akey[NB] | aidx[NB] | ylpart[NB] (float2)
    float*  fpart  = (float*)d_ws;
    float*  spart  = fpart + (size_t)NB * ROW_L;
    float*  akey   = spart + NB;
    int*    aidx   = (int*)(akey + NB);
    float2* ylpart = (float2*)(aidx + NB);

    k1_main<<<NB, K1_TPB, 0, stream>>>(x, y, lin, fb, wps, bps, out,
                                       fpart, spart, akey, aidx, ylpart, N);
    k2_final<<<NB + 1, 512, 0, stream>>>(x, y, lin, fb, fpart, spart, akey, aidx,
                                         ylpart, out, N);
}